// Round 4
// baseline (467.895 us; speedup 1.0000x reference)
//
#include <hip/hip_runtime.h>
#include <hip/hip_bf16.h>

// Problem constants (fixed in the reference file)
constexpr int S      = 512;
constexpr int D      = 768;
constexpr int H_IMG  = 1024;
constexpr int W_IMG  = 768;
constexpr int STRIDE = 8;
constexpr int R  = H_IMG / STRIDE;   // 128
constexpr int C  = W_IMG / STRIDE;   // 96
constexpr int RC = R * C;            // 12288

typedef float f32x4 __attribute__((ext_vector_type(4)));  // native vec for nt-store

// ---------------------------------------------------------------------------
// Phase 1: per-batch segmentation. One block of S threads per batch.
// ---------------------------------------------------------------------------
__global__ void seg_kernel(const int* __restrict__ coors,
                           const int* __restrict__ mask,
                           const int* __restrict__ stride_ptr,
                           int* __restrict__ wstart,
                           int* __restrict__ wcnt,
                           int* __restrict__ wbox,
                           int* __restrict__ nwords_arr) {
    const int b = blockIdx.x;
    const int t = threadIdx.x;

    __shared__ int s_nvalid;
    __shared__ int scan[S];
    __shared__ int sstart[S];

    if (t == 0) s_nvalid = S;
    __syncthreads();
    if (mask[b * S + t] == 0) atomicMin(&s_nvalid, t);
    __syncthreads();
    const int nv = s_nvalid;               // tokens [0, nv) are valid
    const bool valid = t < nv;

    const int4 c4 = *(const int4*)(coors + (size_t)(b * S + t) * 4);
    bool same = false;
    if (t > 0) {
        const int4 p4 = *(const int4*)(coors + (size_t)(b * S + t - 1) * 4);
        same = (c4.x == p4.x) && (c4.y == p4.y) && (c4.z == p4.z) && (c4.w == p4.w);
    }
    const int nw = (valid && (t == 0 || !same)) ? 1 : 0;

    scan[t] = nw;
    __syncthreads();
    for (int off = 1; off < S; off <<= 1) {   // Hillis-Steele inclusive scan
        int v = scan[t] + ((t >= off) ? scan[t - off] : 0);
        __syncthreads();
        scan[t] = v;
        __syncthreads();
    }

    const int stride = *stride_ptr;
    if (nw) {
        const int w = scan[t] - 1;         // this token starts word w
        sstart[w] = t;
        int* bx = wbox + ((size_t)b * S + w) * 4;
        bx[0] = c4.y / stride;             // r0
        bx[1] = c4.w / stride;             // r1
        bx[2] = c4.x / stride;             // c0
        bx[3] = c4.z / stride;             // c1
    }
    __syncthreads();

    const int NW = scan[S - 1];            // total words
    if (t == 0) nwords_arr[b] = NW;
    if (t < NW) {
        const int st  = sstart[t];
        const int nxt = (t + 1 < NW) ? sstart[t + 1] : nv;
        wstart[b * S + t] = st;
        wcnt[b * S + t]   = nxt - st;
    }
}

// ---------------------------------------------------------------------------
// Phase 2: valw[b][w][:] = mean of embeddings of word (w-1); zeros for w==0.
// ---------------------------------------------------------------------------
__global__ void mean_kernel(const float* __restrict__ emb,
                            const int* __restrict__ wstart,
                            const int* __restrict__ wcnt,
                            const int* __restrict__ nwords_arr,
                            float* __restrict__ valw) {
    const int w = blockIdx.x;
    const int b = blockIdx.y;
    if (w >= nwords_arr[b]) return;

    float4* out4 = (float4*)(valw + ((size_t)b * S + w) * D);
    const int t = threadIdx.x;             // 0..191
    if (w == 0) { out4[t] = make_float4(0.f, 0.f, 0.f, 0.f); return; }

    const int pst  = wstart[b * S + w - 1];
    const int pcnt = wcnt[b * S + w - 1];
    const float inv = 1.0f / (float)max(pcnt, 1);
    const float4* e4 = (const float4*)(emb + ((size_t)b * S + pst) * D);
    float4 s = make_float4(0.f, 0.f, 0.f, 0.f);
    for (int k = 0; k < pcnt; ++k) {
        float4 v = e4[(size_t)k * (D / 4) + t];
        s.x += v.x; s.y += v.y; s.z += v.z; s.w += v.w;
    }
    out4[t] = make_float4(s.x * inv, s.y * inv, s.z * inv, s.w * inv);
}

// ---------------------------------------------------------------------------
// Phase 3: last[b][rc] = max word index covering the pixel (-1 if none).
// ---------------------------------------------------------------------------
__global__ void last_kernel(const int* __restrict__ wbox,
                            const int* __restrict__ nwords_arr,
                            int* __restrict__ last) {
    const int b  = blockIdx.y;
    const int NW = nwords_arr[b];

    __shared__ int4 sbox[S];
    for (int i = threadIdx.x; i < NW; i += blockDim.x)
        sbox[i] = ((const int4*)wbox)[b * S + i];
    __syncthreads();

    const int rc = blockIdx.x * blockDim.x + threadIdx.x;
    const int r  = rc / C;
    const int c  = rc % C;
    int w = -1;
    for (int i = 0; i < NW; ++i) {
        const int4 bx = sbox[i];   // broadcast read
        if (r >= bx.x && r < bx.y && c >= bx.z && c < bx.w) w = i;
    }
    last[b * RC + rc] = w;
}

// ---------------------------------------------------------------------------
// Phase 4: scatter word means into the grid.
// Thread = (b, d-quad, 8 pixels): 2 int4 last-reads, 8 float4 gathers
// (cached; valw is L2-reused across blocks), register transpose, 8 coalesced
// NON-TEMPORAL f32x4 stores (nt: no L2 write-allocate pollution of valw/last).
// grid (RC/8/128, D/4, B), block 128.
// ---------------------------------------------------------------------------
__global__ void __launch_bounds__(128, 4)
out_kernel(const float* __restrict__ valw,
           const int* __restrict__ last,
           float* __restrict__ out) {
    const int rc8 = blockIdx.x * blockDim.x + threadIdx.x;  // 0..RC/8-1
    const int d4  = blockIdx.y;                             // 0..D/4-1
    const int b   = blockIdx.z;

    const int4* lp = (const int4*)(last + (size_t)b * RC) + rc8 * 2;
    const int4 la = lp[0];
    const int4 lb = lp[1];
    const float* vb = valw + (size_t)b * S * D + d4 * 4;
    const float4 z = make_float4(0.f, 0.f, 0.f, 0.f);
    const float4 v0 = (la.x >= 0) ? *(const float4*)(vb + (size_t)la.x * D) : z;
    const float4 v1 = (la.y >= 0) ? *(const float4*)(vb + (size_t)la.y * D) : z;
    const float4 v2 = (la.z >= 0) ? *(const float4*)(vb + (size_t)la.z * D) : z;
    const float4 v3 = (la.w >= 0) ? *(const float4*)(vb + (size_t)la.w * D) : z;
    const float4 v4 = (lb.x >= 0) ? *(const float4*)(vb + (size_t)lb.x * D) : z;
    const float4 v5 = (lb.y >= 0) ? *(const float4*)(vb + (size_t)lb.y * D) : z;
    const float4 v6 = (lb.z >= 0) ? *(const float4*)(vb + (size_t)lb.z * D) : z;
    const float4 v7 = (lb.w >= 0) ? *(const float4*)(vb + (size_t)lb.w * D) : z;

    f32x4* ob = (f32x4*)(out + ((size_t)(b * D + d4 * 4)) * RC) + rc8 * 2;
    constexpr int STRIDE4 = RC / 4;   // 3072 f32x4 per (d) plane
    __builtin_nontemporal_store((f32x4){v0.x, v1.x, v2.x, v3.x}, ob + 0);
    __builtin_nontemporal_store((f32x4){v4.x, v5.x, v6.x, v7.x}, ob + 1);
    __builtin_nontemporal_store((f32x4){v0.y, v1.y, v2.y, v3.y}, ob + STRIDE4);
    __builtin_nontemporal_store((f32x4){v4.y, v5.y, v6.y, v7.y}, ob + STRIDE4 + 1);
    __builtin_nontemporal_store((f32x4){v0.z, v1.z, v2.z, v3.z}, ob + 2 * STRIDE4);
    __builtin_nontemporal_store((f32x4){v4.z, v5.z, v6.z, v7.z}, ob + 2 * STRIDE4 + 1);
    __builtin_nontemporal_store((f32x4){v0.w, v1.w, v2.w, v3.w}, ob + 3 * STRIDE4);
    __builtin_nontemporal_store((f32x4){v4.w, v5.w, v6.w, v7.w}, ob + 3 * STRIDE4 + 1);
}

// ---------------------------------------------------------------------------
extern "C" void kernel_launch(void* const* d_in, const int* in_sizes, int n_in,
                              void* d_out, int out_size, void* d_ws, size_t ws_size,
                              hipStream_t stream) {
    const float* emb        = (const float*)d_in[0];
    const int*   coors      = (const int*)d_in[1];
    const int*   mask       = (const int*)d_in[2];
    const int*   stride_ptr = (const int*)d_in[5];
    float*       out        = (float*)d_out;

    const int Bv = in_sizes[2] / S;   // 8

    // Workspace layout (ws re-poisoned every call; each buffer written before read)
    float* valw   = (float*)d_ws;                       // Bv*S*D floats
    int*   last   = (int*)(valw + (size_t)Bv * S * D);  // Bv*RC ints
    int*   wstart = last + (size_t)Bv * RC;             // Bv*S
    int*   wcnt   = wstart + (size_t)Bv * S;            // Bv*S
    int*   wbox   = wcnt + (size_t)Bv * S;              // Bv*S*4
    int*   nwords = wbox + (size_t)Bv * S * 4;          // Bv

    seg_kernel<<<Bv, S, 0, stream>>>(coors, mask, stride_ptr, wstart, wcnt, wbox, nwords);
    mean_kernel<<<dim3(S, Bv), D / 4, 0, stream>>>(emb, wstart, wcnt, nwords, valw);
    last_kernel<<<dim3(RC / 256, Bv), 256, 0, stream>>>(wbox, nwords, last);
    out_kernel<<<dim3(RC / 8 / 128, D / 4, Bv), 128, 0, stream>>>(valw, last, out);
}

// Round 5
// 366.764 us; speedup vs baseline: 1.2757x; 1.2757x over previous
//
#include <hip/hip_runtime.h>
#include <hip/hip_bf16.h>

// Problem constants (fixed in the reference file)
constexpr int S      = 512;
constexpr int D      = 768;
constexpr int H_IMG  = 1024;
constexpr int W_IMG  = 768;
constexpr int STRIDE = 8;
constexpr int R  = H_IMG / STRIDE;   // 128
constexpr int C  = W_IMG / STRIDE;   // 96
constexpr int RC = R * C;            // 12288

// ---------------------------------------------------------------------------
// Phase 1: per-batch segmentation. One block of S threads per batch.
// ---------------------------------------------------------------------------
__global__ void seg_kernel(const int* __restrict__ coors,
                           const int* __restrict__ mask,
                           const int* __restrict__ stride_ptr,
                           int* __restrict__ wstart,
                           int* __restrict__ wcnt,
                           int* __restrict__ wbox,
                           int* __restrict__ nwords_arr) {
    const int b = blockIdx.x;
    const int t = threadIdx.x;

    __shared__ int s_nvalid;
    __shared__ int scan[S];
    __shared__ int sstart[S];

    if (t == 0) s_nvalid = S;
    __syncthreads();
    if (mask[b * S + t] == 0) atomicMin(&s_nvalid, t);
    __syncthreads();
    const int nv = s_nvalid;               // tokens [0, nv) are valid
    const bool valid = t < nv;

    const int4 c4 = *(const int4*)(coors + (size_t)(b * S + t) * 4);
    bool same = false;
    if (t > 0) {
        const int4 p4 = *(const int4*)(coors + (size_t)(b * S + t - 1) * 4);
        same = (c4.x == p4.x) && (c4.y == p4.y) && (c4.z == p4.z) && (c4.w == p4.w);
    }
    const int nw = (valid && (t == 0 || !same)) ? 1 : 0;

    scan[t] = nw;
    __syncthreads();
    for (int off = 1; off < S; off <<= 1) {   // Hillis-Steele inclusive scan
        int v = scan[t] + ((t >= off) ? scan[t - off] : 0);
        __syncthreads();
        scan[t] = v;
        __syncthreads();
    }

    const int stride = *stride_ptr;
    if (nw) {
        const int w = scan[t] - 1;         // this token starts word w
        sstart[w] = t;
        int* bx = wbox + ((size_t)b * S + w) * 4;
        bx[0] = c4.y / stride;             // r0
        bx[1] = c4.w / stride;             // r1
        bx[2] = c4.x / stride;             // c0
        bx[3] = c4.z / stride;             // c1
    }
    __syncthreads();

    const int NW = scan[S - 1];            // total words
    if (t == 0) nwords_arr[b] = NW;
    if (t < NW) {
        const int st  = sstart[t];
        const int nxt = (t + 1 < NW) ? sstart[t + 1] : nv;
        wstart[b * S + t] = st;
        wcnt[b * S + t]   = nxt - st;
    }
}

// ---------------------------------------------------------------------------
// Phase 2: valw[b][w][:] = mean of embeddings of word (w-1); zeros for w==0.
// ---------------------------------------------------------------------------
__global__ void mean_kernel(const float* __restrict__ emb,
                            const int* __restrict__ wstart,
                            const int* __restrict__ wcnt,
                            const int* __restrict__ nwords_arr,
                            float* __restrict__ valw) {
    const int w = blockIdx.x;
    const int b = blockIdx.y;
    if (w >= nwords_arr[b]) return;

    float4* out4 = (float4*)(valw + ((size_t)b * S + w) * D);
    const int t = threadIdx.x;             // 0..191
    if (w == 0) { out4[t] = make_float4(0.f, 0.f, 0.f, 0.f); return; }

    const int pst  = wstart[b * S + w - 1];
    const int pcnt = wcnt[b * S + w - 1];
    const float inv = 1.0f / (float)max(pcnt, 1);
    const float4* e4 = (const float4*)(emb + ((size_t)b * S + pst) * D);
    float4 s = make_float4(0.f, 0.f, 0.f, 0.f);
    for (int k = 0; k < pcnt; ++k) {
        float4 v = e4[(size_t)k * (D / 4) + t];
        s.x += v.x; s.y += v.y; s.z += v.z; s.w += v.w;
    }
    out4[t] = make_float4(s.x * inv, s.y * inv, s.z * inv, s.w * inv);
}

// ---------------------------------------------------------------------------
// Phase 3: last[b][rc] = max word index covering the pixel (-1 if none).
// ---------------------------------------------------------------------------
__global__ void last_kernel(const int* __restrict__ wbox,
                            const int* __restrict__ nwords_arr,
                            int* __restrict__ last) {
    const int b  = blockIdx.y;
    const int NW = nwords_arr[b];

    __shared__ int4 sbox[S];
    for (int i = threadIdx.x; i < NW; i += blockDim.x)
        sbox[i] = ((const int4*)wbox)[b * S + i];
    __syncthreads();

    const int rc = blockIdx.x * blockDim.x + threadIdx.x;
    const int r  = rc / C;
    const int c  = rc % C;
    int w = -1;
    for (int i = 0; i < NW; ++i) {
        const int4 bx = sbox[i];   // broadcast read
        if (r >= bx.x && r < bx.y && c >= bx.z && c < bx.w) w = i;
    }
    last[b * RC + rc] = w;
}

// ---------------------------------------------------------------------------
// Phase 4: scatter word means into the grid.
// Thread = (b, d-quad, pixel-quad): 1 int4 last-read, 4 float4 gathers,
// register transpose, 4 coalesced float4 stores (plain stores — nt measured
// +100us regression in R4: L2 write-combining is the fast path for streaming).
// grid (RC/4/256, D/4, B), block 256.
// ---------------------------------------------------------------------------
__global__ void out_kernel(const float* __restrict__ valw,
                           const int* __restrict__ last,
                           float* __restrict__ out) {
    const int rc4 = blockIdx.x * blockDim.x + threadIdx.x;  // 0..RC/4-1
    const int d4  = blockIdx.y;                             // 0..D/4-1
    const int b   = blockIdx.z;

    const int4 l4 = ((const int4*)(last + (size_t)b * RC))[rc4];
    const float* vb = valw + (size_t)b * S * D + d4 * 4;
    const float4 z = make_float4(0.f, 0.f, 0.f, 0.f);
    const float4 v0 = (l4.x >= 0) ? *(const float4*)(vb + (size_t)l4.x * D) : z;
    const float4 v1 = (l4.y >= 0) ? *(const float4*)(vb + (size_t)l4.y * D) : z;
    const float4 v2 = (l4.z >= 0) ? *(const float4*)(vb + (size_t)l4.z * D) : z;
    const float4 v3 = (l4.w >= 0) ? *(const float4*)(vb + (size_t)l4.w * D) : z;

    float4* ob = (float4*)(out + ((size_t)(b * D + d4 * 4)) * RC) + rc4;
    constexpr int STRIDE4 = RC / 4;   // 3072 float4 per (d) plane
    ob[0]           = make_float4(v0.x, v1.x, v2.x, v3.x);
    ob[STRIDE4]     = make_float4(v0.y, v1.y, v2.y, v3.y);
    ob[2 * STRIDE4] = make_float4(v0.z, v1.z, v2.z, v3.z);
    ob[3 * STRIDE4] = make_float4(v0.w, v1.w, v2.w, v3.w);
}

// ---------------------------------------------------------------------------
extern "C" void kernel_launch(void* const* d_in, const int* in_sizes, int n_in,
                              void* d_out, int out_size, void* d_ws, size_t ws_size,
                              hipStream_t stream) {
    const float* emb        = (const float*)d_in[0];
    const int*   coors      = (const int*)d_in[1];
    const int*   mask       = (const int*)d_in[2];
    const int*   stride_ptr = (const int*)d_in[5];
    float*       out        = (float*)d_out;

    const int Bv = in_sizes[2] / S;   // 8

    // Workspace layout (ws re-poisoned every call; each buffer written before read)
    float* valw   = (float*)d_ws;                       // Bv*S*D floats
    int*   last   = (int*)(valw + (size_t)Bv * S * D);  // Bv*RC ints
    int*   wstart = last + (size_t)Bv * RC;             // Bv*S
    int*   wcnt   = wstart + (size_t)Bv * S;            // Bv*S
    int*   wbox   = wcnt + (size_t)Bv * S;              // Bv*S*4
    int*   nwords = wbox + (size_t)Bv * S * 4;          // Bv

    seg_kernel<<<Bv, S, 0, stream>>>(coors, mask, stride_ptr, wstart, wcnt, wbox, nwords);
    mean_kernel<<<dim3(S, Bv), D / 4, 0, stream>>>(emb, wstart, wcnt, nwords, valw);
    last_kernel<<<dim3(RC / 256, Bv), 256, 0, stream>>>(wbox, nwords, last);
    out_kernel<<<dim3(RC / 4 / 256, D / 4, Bv), 256, 0, stream>>>(valw, last, out);
}

// Round 6
// 357.480 us; speedup vs baseline: 1.3089x; 1.0260x over previous
//
#include <hip/hip_runtime.h>
#include <hip/hip_bf16.h>

// Problem constants (fixed in the reference file)
constexpr int S      = 512;
constexpr int D      = 768;
constexpr int H_IMG  = 1024;
constexpr int W_IMG  = 768;
constexpr int STRIDE = 8;
constexpr int R  = H_IMG / STRIDE;   // 128
constexpr int C  = W_IMG / STRIDE;   // 96
constexpr int RC = R * C;            // 12288

// ---------------------------------------------------------------------------
// Phase 1: per-batch segmentation. One block of S threads per batch.
// ---------------------------------------------------------------------------
__global__ void seg_kernel(const int* __restrict__ coors,
                           const int* __restrict__ mask,
                           const int* __restrict__ stride_ptr,
                           int* __restrict__ wstart,
                           int* __restrict__ wcnt,
                           int* __restrict__ wbox,
                           int* __restrict__ nwords_arr) {
    const int b = blockIdx.x;
    const int t = threadIdx.x;

    __shared__ int s_nvalid;
    __shared__ int scan[S];
    __shared__ int sstart[S];

    if (t == 0) s_nvalid = S;
    __syncthreads();
    if (mask[b * S + t] == 0) atomicMin(&s_nvalid, t);
    __syncthreads();
    const int nv = s_nvalid;               // tokens [0, nv) are valid
    const bool valid = t < nv;

    const int4 c4 = *(const int4*)(coors + (size_t)(b * S + t) * 4);
    bool same = false;
    if (t > 0) {
        const int4 p4 = *(const int4*)(coors + (size_t)(b * S + t - 1) * 4);
        same = (c4.x == p4.x) && (c4.y == p4.y) && (c4.z == p4.z) && (c4.w == p4.w);
    }
    const int nw = (valid && (t == 0 || !same)) ? 1 : 0;

    scan[t] = nw;
    __syncthreads();
    for (int off = 1; off < S; off <<= 1) {   // Hillis-Steele inclusive scan
        int v = scan[t] + ((t >= off) ? scan[t - off] : 0);
        __syncthreads();
        scan[t] = v;
        __syncthreads();
    }

    const int stride = *stride_ptr;
    if (nw) {
        const int w = scan[t] - 1;         // this token starts word w
        sstart[w] = t;
        int* bx = wbox + ((size_t)b * S + w) * 4;
        bx[0] = c4.y / stride;             // r0
        bx[1] = c4.w / stride;             // r1
        bx[2] = c4.x / stride;             // c0
        bx[3] = c4.z / stride;             // c1
    }
    __syncthreads();

    const int NW = scan[S - 1];            // total words
    if (t == 0) nwords_arr[b] = NW;
    if (t < NW) {
        const int st  = sstart[t];
        const int nxt = (t + 1 < NW) ? sstart[t + 1] : nv;
        wstart[b * S + t] = st;
        wcnt[b * S + t]   = nxt - st;
    }
}

// ---------------------------------------------------------------------------
// Phase 2: valw[b][w][:] = mean of embeddings of word (w-1); zeros for w==0.
// ---------------------------------------------------------------------------
__global__ void mean_kernel(const float* __restrict__ emb,
                            const int* __restrict__ wstart,
                            const int* __restrict__ wcnt,
                            const int* __restrict__ nwords_arr,
                            float* __restrict__ valw) {
    const int w = blockIdx.x;
    const int b = blockIdx.y;
    if (w >= nwords_arr[b]) return;

    float4* out4 = (float4*)(valw + ((size_t)b * S + w) * D);
    const int t = threadIdx.x;             // 0..191
    if (w == 0) { out4[t] = make_float4(0.f, 0.f, 0.f, 0.f); return; }

    const int pst  = wstart[b * S + w - 1];
    const int pcnt = wcnt[b * S + w - 1];
    const float inv = 1.0f / (float)max(pcnt, 1);
    const float4* e4 = (const float4*)(emb + ((size_t)b * S + pst) * D);
    float4 s = make_float4(0.f, 0.f, 0.f, 0.f);
    for (int k = 0; k < pcnt; ++k) {
        float4 v = e4[(size_t)k * (D / 4) + t];
        s.x += v.x; s.y += v.y; s.z += v.z; s.w += v.w;
    }
    out4[t] = make_float4(s.x * inv, s.y * inv, s.z * inv, s.w * inv);
}

// ---------------------------------------------------------------------------
// Phase 3: last[b][rc] = max word index covering the pixel (-1 if none).
// ---------------------------------------------------------------------------
__global__ void last_kernel(const int* __restrict__ wbox,
                            const int* __restrict__ nwords_arr,
                            int* __restrict__ last) {
    const int b  = blockIdx.y;
    const int NW = nwords_arr[b];

    __shared__ int4 sbox[S];
    for (int i = threadIdx.x; i < NW; i += blockDim.x)
        sbox[i] = ((const int4*)wbox)[b * S + i];
    __syncthreads();

    const int rc = blockIdx.x * blockDim.x + threadIdx.x;
    const int r  = rc / C;
    const int c  = rc % C;
    int w = -1;
    for (int i = 0; i < NW; ++i) {
        const int4 bx = sbox[i];   // broadcast read
        if (r >= bx.x && r < bx.y && c >= bx.z && c < bx.w) w = i;
    }
    last[b * RC + rc] = w;
}

// ---------------------------------------------------------------------------
// Phase 4: scatter word means into the grid — R1's measured-best pattern:
// thread = (b, d, pixel-quad): 1 int4 last-read, 4 scalar gathers (L2-hit),
// ONE coalesced float4 store. The whole dispatch is a single linear write
// sweep of the 302 MB output (best HBM sequentiality; R2/R5's 4-plane
// strided-store variant measured +27us, R4's nt-store +102us).
// 3D grid removes the R1 div/mod. grid (RC/4/256, D, B), block 256.
// ---------------------------------------------------------------------------
__global__ void out_kernel(const float* __restrict__ valw,
                           const int* __restrict__ last,
                           float* __restrict__ out) {
    const int rc4 = blockIdx.x * blockDim.x + threadIdx.x;  // 0..RC/4-1
    const int d   = blockIdx.y;                             // 0..D-1
    const int b   = blockIdx.z;

    const int4 l4 = ((const int4*)(last + (size_t)b * RC))[rc4];
    const float* vb = valw + (size_t)b * S * D + d;
    float4 o;
    o.x = (l4.x >= 0) ? vb[(size_t)l4.x * D] : 0.0f;
    o.y = (l4.y >= 0) ? vb[(size_t)l4.y * D] : 0.0f;
    o.z = (l4.z >= 0) ? vb[(size_t)l4.z * D] : 0.0f;
    o.w = (l4.w >= 0) ? vb[(size_t)l4.w * D] : 0.0f;
    ((float4*)(out + ((size_t)(b * D + d)) * RC))[rc4] = o;
}

// ---------------------------------------------------------------------------
extern "C" void kernel_launch(void* const* d_in, const int* in_sizes, int n_in,
                              void* d_out, int out_size, void* d_ws, size_t ws_size,
                              hipStream_t stream) {
    const float* emb        = (const float*)d_in[0];
    const int*   coors      = (const int*)d_in[1];
    const int*   mask       = (const int*)d_in[2];
    const int*   stride_ptr = (const int*)d_in[5];
    float*       out        = (float*)d_out;

    const int Bv = in_sizes[2] / S;   // 8

    // Workspace layout (ws re-poisoned every call; each buffer written before read)
    float* valw   = (float*)d_ws;                       // Bv*S*D floats
    int*   last   = (int*)(valw + (size_t)Bv * S * D);  // Bv*RC ints
    int*   wstart = last + (size_t)Bv * RC;             // Bv*S
    int*   wcnt   = wstart + (size_t)Bv * S;            // Bv*S
    int*   wbox   = wcnt + (size_t)Bv * S;              // Bv*S*4
    int*   nwords = wbox + (size_t)Bv * S * 4;          // Bv

    seg_kernel<<<Bv, S, 0, stream>>>(coors, mask, stride_ptr, wstart, wcnt, wbox, nwords);
    mean_kernel<<<dim3(S, Bv), D / 4, 0, stream>>>(emb, wstart, wcnt, nwords, valw);
    last_kernel<<<dim3(RC / 256, Bv), 256, 0, stream>>>(wbox, nwords, last);
    out_kernel<<<dim3(RC / 4 / 256, D, Bv), 256, 0, stream>>>(valw, last, out);
}